// Round 1
// baseline (6394.247 us; speedup 1.0000x reference)
//
#include <hip/hip_runtime.h>
#include <hip/hip_bf16.h>
#include <math.h>

#define S_LEN 1024
#define T_LEN 512
#define G_NUM 1024
#define NLOC  50000
#define HID   512
#define INP   608     // 512 + 64 + 32
#define OUTD  1088    // 2*HID + 64
#define GRU_WGS 32

typedef float f32x4 __attribute__((ext_vector_type(4)));
typedef short bf16x8 __attribute__((ext_vector_type(8)));

// ---------------------------------------------------------------- init ------
__global__ __launch_bounds__(1024) void k_init(int* cnt, float* hbuf,
                                               const int* counts, int* offs) {
    __shared__ int sh[1024];
    int tid = threadIdx.x;
    cnt[tid] = 0;
    hbuf[tid] = 0.0f;              // 2 x 512 double buffer
    sh[tid] = counts[tid];
    __syncthreads();
    for (int st = 1; st < 1024; st <<= 1) {
        int v = (tid >= st) ? sh[tid - st] : 0;
        __syncthreads();
        sh[tid] += v;
        __syncthreads();
    }
    offs[tid] = sh[tid] - counts[tid];   // exclusive prefix
}

// ------------------------------------------------------- history features ---
__global__ __launch_bounds__(256) void k_feats(
    const int* __restrict__ hloc, const int* __restrict__ hclu,
    const int* __restrict__ htim, const int* __restrict__ counts,
    const int* __restrict__ offs,
    const float* __restrict__ emb_loc, const float* __restrict__ emb_clu,
    const float* __restrict__ emb_tim, float* __restrict__ feats) {
    int g = blockIdx.x, tid = threadIdx.x;
    __shared__ int iloc[64], iclu[64];
    __shared__ int itim0;
    int off = offs[g], cn = counts[g];
    if (tid < cn) { iloc[tid] = hloc[off + tid]; iclu[tid] = hclu[off + tid]; }
    if (tid == 0) itim0 = htim[off];
    __syncthreads();
    float inv = 1.0f / (float)cn;
    for (int d = tid; d < 512; d += 256) {
        float s = 0.f;
        for (int i = 0; i < cn; ++i) s += emb_loc[iloc[i] * 512 + d];
        feats[g * INP + d] = s * inv;
    }
    for (int d = tid; d < 64; d += 256) {
        float s = 0.f;
        for (int i = 0; i < cn; ++i) s += emb_clu[iclu[i] * 64 + d];
        feats[g * INP + 512 + d] = s * inv;
    }
    for (int d = tid; d < 32; d += 256)
        feats[g * INP + 576 + d] = emb_tim[itim0 * 32 + d];
}

// ------------------------------------------------------------ x features ----
__global__ __launch_bounds__(256) void k_xfeat(
    const int* __restrict__ loc, const int* __restrict__ clu,
    const int* __restrict__ tim,
    const float* __restrict__ emb_loc, const float* __restrict__ emb_clu,
    const float* __restrict__ emb_tim, float* __restrict__ x) {
    int s = blockIdx.x, tid = threadIdx.x;
    int il = loc[s], ic = clu[s], it = tim[s];
    for (int d = tid; d < 512; d += 256) x[s * INP + d] = emb_loc[il * 512 + d];
    for (int d = tid; d < 64; d += 256) x[s * INP + 512 + d] = emb_clu[ic * 64 + d];
    for (int d = tid; d < 32; d += 256) x[s * INP + 576 + d] = emb_tim[it * 32 + d];
}

// ---------------------------------------------- generic 8-row fp32 GEMM -----
// out[r][c] = act( A[r][:] . W[c][:] + bias[c] ), A rows x INP, W N x INP
__global__ __launch_bounds__(256) void k_gemm8(
    const float* __restrict__ A, const float* __restrict__ W,
    const float* __restrict__ bias, float* __restrict__ out,
    int ldout, int act) {
    __shared__ float ash[8][INP];
    int r0 = blockIdx.x * 8, c0 = blockIdx.y * 512;
    int tid = threadIdx.x;
    for (int i = tid; i < 8 * INP; i += 256)
        ash[i / INP][i % INP] = A[(r0 + i / INP) * INP + (i % INP)];
    __syncthreads();
    for (int cc = 0; cc < 2; ++cc) {
        int c = c0 + cc * 256 + tid;
        float acc[8];
#pragma unroll
        for (int r = 0; r < 8; ++r) acc[r] = 0.f;
        const float* wr = &W[(long)c * INP];
        for (int k = 0; k < INP; k += 4) {
            float4 wv = *(const float4*)&wr[k];
#pragma unroll
            for (int r = 0; r < 8; ++r) {
                float4 av = *(const float4*)&ash[r][k];
                acc[r] += av.x * wv.x + av.y * wv.y + av.z * wv.z + av.w * wv.w;
            }
        }
#pragma unroll
        for (int r = 0; r < 8; ++r) {
            float v = acc[r] + bias[c];
            if (act) v = tanhf(v);
            out[(long)(r0 + r) * ldout + c] = v;
        }
    }
}

// ------------------------------------------------------------- GRU ----------
__global__ __launch_bounds__(256) void k_gru(
    const float* __restrict__ w_hh, const float* __restrict__ b_hh,
    const float* __restrict__ gx, float* __restrict__ hbuf,
    float* __restrict__ outmat, int* __restrict__ cnt) {
    __shared__ __hip_bfloat16 wsh[48 * 513];
    const int wg = blockIdx.x;
    const int tid = threadIdx.x;
    for (int i = tid; i < 48 * 512; i += 256) {
        int row = i >> 9, k = i & 511;
        int gt = row >> 4, jl = row & 15;
        wsh[row * 513 + k] = __float2bfloat16(w_hh[((gt * 512) + wg * 16 + jl) * 512 + k]);
    }
    const int grp = tid >> 4;
    const int lane = tid & 15;
    const int j = wg * 16 + grp;
    const float bhr = b_hh[j], bhz = b_hh[512 + j], bhn = b_hh[1024 + j];
    __syncthreads();
    const __hip_bfloat16* wr = &wsh[grp * 513];
    const __hip_bfloat16* wz = &wsh[(16 + grp) * 513];
    const __hip_bfloat16* wn = &wsh[(32 + grp) * 513];
    for (int t = 0; t < S_LEN; ++t) {
        float xr = 0.f, xz = 0.f, xn = 0.f;
        if (lane == 0) {
            xr = gx[t * 1536 + j];
            xz = gx[t * 1536 + 512 + j];
            xn = gx[t * 1536 + 1024 + j];
        }
        const float* hprev = hbuf + ((t + 1) & 1) * HID;
        float sr = 0.f, sz = 0.f, sn = 0.f;
#pragma unroll
        for (int kk = 0; kk < 32; ++kk) {
            int k = lane + kk * 16;
            float hv = __hip_atomic_load(hprev + k, __ATOMIC_RELAXED, __HIP_MEMORY_SCOPE_AGENT);
            sr += __bfloat162float(wr[k]) * hv;
            sz += __bfloat162float(wz[k]) * hv;
            sn += __bfloat162float(wn[k]) * hv;
        }
#pragma unroll
        for (int off = 8; off; off >>= 1) {
            sr += __shfl_xor(sr, off);
            sz += __shfl_xor(sz, off);
            sn += __shfl_xor(sn, off);
        }
        if (lane == 0) {
            float r = 1.f / (1.f + __expf(-(xr + sr + bhr)));
            float z = 1.f / (1.f + __expf(-(xz + sz + bhz)));
            float n = tanhf(xn + r * (sn + bhn));
            float hold = __hip_atomic_load(hprev + j, __ATOMIC_RELAXED, __HIP_MEMORY_SCOPE_AGENT);
            float hnew = (1.f - z) * n + z * hold;
            __hip_atomic_store(hbuf + (t & 1) * HID + j, hnew, __ATOMIC_RELAXED, __HIP_MEMORY_SCOPE_AGENT);
            if (t >= S_LEN - T_LEN) outmat[(t - (S_LEN - T_LEN)) * OUTD + j] = hnew;
        }
        __threadfence();
        __syncthreads();
        if (tid == 0) {
            __hip_atomic_fetch_add(cnt + t, 1, __ATOMIC_RELEASE, __HIP_MEMORY_SCOPE_AGENT);
            while (__hip_atomic_load(cnt + t, __ATOMIC_ACQUIRE, __HIP_MEMORY_SCOPE_AGENT) < GRU_WGS) {}
        }
        __syncthreads();
    }
}

// ------------------------------------------------------- attention ----------
__global__ __launch_bounds__(256) void k_attn(
    const float* __restrict__ history, const float* __restrict__ emb_uid,
    const int* __restrict__ uid, float* __restrict__ outmat) {
    __shared__ float qsh[8][512];
    __shared__ float psh[8][1024];
    __shared__ float sc[4];
    int r0 = blockIdx.x * 8, tid = threadIdx.x;
    for (int i = tid; i < 8 * 512; i += 256)
        qsh[i >> 9][i & 511] = outmat[(r0 + (i >> 9)) * OUTD + (i & 511)];
    __syncthreads();
    // logits
    for (int cc = 0; cc < 4; ++cc) {
        int g = cc * 256 + tid;
        float acc[8];
#pragma unroll
        for (int r = 0; r < 8; ++r) acc[r] = 0.f;
        const float* hrow = &history[g * 512];
        for (int k = 0; k < 512; k += 4) {
            float4 hv = *(const float4*)&hrow[k];
#pragma unroll
            for (int r = 0; r < 8; ++r) {
                float4 qv = *(const float4*)&qsh[r][k];
                acc[r] += qv.x * hv.x + qv.y * hv.y + qv.z * hv.z + qv.w * hv.w;
            }
        }
#pragma unroll
        for (int r = 0; r < 8; ++r) psh[r][g] = acc[r];
    }
    __syncthreads();
    // softmax per row
    for (int r = 0; r < 8; ++r) {
        float m = -1e30f;
        for (int cc = 0; cc < 4; ++cc) m = fmaxf(m, psh[r][cc * 256 + tid]);
#pragma unroll
        for (int off = 32; off; off >>= 1) m = fmaxf(m, __shfl_xor(m, off));
        if ((tid & 63) == 0) sc[tid >> 6] = m;
        __syncthreads();
        m = fmaxf(fmaxf(sc[0], sc[1]), fmaxf(sc[2], sc[3]));
        __syncthreads();
        float ss = 0.f;
        for (int cc = 0; cc < 4; ++cc) {
            int g = cc * 256 + tid;
            float e = __expf(psh[r][g] - m);
            psh[r][g] = e;
            ss += e;
        }
#pragma unroll
        for (int off = 32; off; off >>= 1) ss += __shfl_xor(ss, off);
        if ((tid & 63) == 0) sc[tid >> 6] = ss;
        __syncthreads();
        ss = sc[0] + sc[1] + sc[2] + sc[3];
        float inv = 1.f / ss;
        for (int cc = 0; cc < 4; ++cc) psh[r][cc * 256 + tid] *= inv;
        __syncthreads();
    }
    // context
    for (int dd = 0; dd < 2; ++dd) {
        int d = dd * 256 + tid;
        float acc[8];
#pragma unroll
        for (int r = 0; r < 8; ++r) acc[r] = 0.f;
        for (int g = 0; g < 1024; ++g) {
            float hv = history[g * 512 + d];
#pragma unroll
            for (int r = 0; r < 8; ++r) acc[r] += psh[r][g] * hv;
        }
#pragma unroll
        for (int r = 0; r < 8; ++r) outmat[(r0 + r) * OUTD + 512 + d] = acc[r];
    }
    // uid embedding
    int u = uid[0];
    for (int i = tid; i < 8 * 64; i += 256)
        outmat[(r0 + (i >> 6)) * OUTD + 1024 + (i & 63)] = emb_uid[u * 64 + (i & 63)];
}

// ----------------------------------------------------------- f32 -> bf16 ----
__global__ __launch_bounds__(256) void k_cvt(const float* __restrict__ in,
                                             __hip_bfloat16* __restrict__ out, int n) {
    int i = blockIdx.x * 256 + threadIdx.x;
    if (i < n) out[i] = __float2bfloat16(in[i]);
}

// -------------------------------------------- final GEMM (bf16 MFMA) --------
// A: T_LEN x OUTD bf16 (row major), W: NLOC x OUTD fp32 -> y = A.W^T + b
__global__ __launch_bounds__(256, 2) void k_final(
    const __hip_bfloat16* __restrict__ Abf, const float* __restrict__ Wf,
    const float* __restrict__ bias, float* __restrict__ y) {
    __shared__ __hip_bfloat16 ash[512 * 40];  // 512 rows x 32 k, stride 40
    __shared__ __hip_bfloat16 bsh[64 * 40];   // 64 cols x 32 k, stride 40
    const int n0 = blockIdx.x * 64;
    const int tid = threadIdx.x;
    const int wave = tid >> 6, lane = tid & 63;
    f32x4 acc[32];
#pragma unroll
    for (int i = 0; i < 32; ++i) acc[i] = (f32x4){0.f, 0.f, 0.f, 0.f};

    for (int kc = 0; kc < 34; ++kc) {
        const int k0 = kc * 32;
        __syncthreads();
        // stage A (already bf16): 2 rows per thread, 64B each
#pragma unroll
        for (int rr = 0; rr < 2; ++rr) {
            int r = tid + rr * 256;
            const uint4* src = (const uint4*)(Abf + r * OUTD + k0);
            uint4 v0 = src[0], v1 = src[1], v2 = src[2], v3 = src[3];
            uint4* dst = (uint4*)(ash + r * 40);
            dst[0] = v0; dst[1] = v1; dst[2] = v2; dst[3] = v3;
        }
        // stage B: fp32 -> bf16, 1/4 row per thread
        {
            int rb = tid >> 2, q = tid & 3;
            int n = n0 + rb;
            float4 w0 = {0.f, 0.f, 0.f, 0.f}, w1 = {0.f, 0.f, 0.f, 0.f};
            if (n < NLOC) {
                const float4* wsrc = (const float4*)(Wf + (long)n * OUTD + k0 + q * 8);
                w0 = wsrc[0]; w1 = wsrc[1];
            }
            __hip_bfloat16* bd = bsh + rb * 40 + q * 8;
            bd[0] = __float2bfloat16(w0.x); bd[1] = __float2bfloat16(w0.y);
            bd[2] = __float2bfloat16(w0.z); bd[3] = __float2bfloat16(w0.w);
            bd[4] = __float2bfloat16(w1.x); bd[5] = __float2bfloat16(w1.y);
            bd[6] = __float2bfloat16(w1.z); bd[7] = __float2bfloat16(w1.w);
        }
        __syncthreads();
        const int nlane = lane & 15, quad = lane >> 4;
        bf16x8 bfrag = *(const bf16x8*)(bsh + (wave * 16 + nlane) * 40 + quad * 8);
#pragma unroll
        for (int mt = 0; mt < 32; ++mt) {
            bf16x8 afrag = *(const bf16x8*)(ash + (mt * 16 + nlane) * 40 + quad * 8);
            acc[mt] = __builtin_amdgcn_mfma_f32_16x16x32_bf16(afrag, bfrag, acc[mt], 0, 0, 0);
        }
    }
    // epilogue: D row = mt*16 + quad*4 + reg, col = n0 + wave*16 + (lane&15)
    const int nlane = lane & 15, quad = lane >> 4;
    const int col = n0 + wave * 16 + nlane;
    if (col < NLOC) {
        float bv = bias[col];
#pragma unroll
        for (int mt = 0; mt < 32; ++mt) {
            int rbase = mt * 16 + quad * 4;
#pragma unroll
            for (int i = 0; i < 4; ++i)
                y[(rbase + i) * NLOC + col] = acc[mt][i] + bv;
        }
    }
}

// ----------------------------------------------------------- row LSE --------
__global__ __launch_bounds__(256) void k_lse(const float* __restrict__ y,
                                             float* __restrict__ lse) {
    __shared__ float sm[4], ssb[4];
    int row = blockIdx.x, tid = threadIdx.x;
    const float* rp = y + (long)row * NLOC;
    float m = -1e30f, s = 0.f;
    for (int i = tid * 4; i < NLOC; i += 1024) {
        float4 v = *(const float4*)&rp[i];
        float mv = fmaxf(fmaxf(v.x, v.y), fmaxf(v.z, v.w));
        if (mv > m) { s *= __expf(m - mv); m = mv; }
        s += __expf(v.x - m) + __expf(v.y - m) + __expf(v.z - m) + __expf(v.w - m);
    }
#pragma unroll
    for (int off = 32; off; off >>= 1) {
        float om = __shfl_xor(m, off), os = __shfl_xor(s, off);
        float nm = fmaxf(m, om);
        s = s * __expf(m - nm) + os * __expf(om - nm);
        m = nm;
    }
    if ((tid & 63) == 0) { sm[tid >> 6] = m; ssb[tid >> 6] = s; }
    __syncthreads();
    if (tid == 0) {
        float M = sm[0], SS = ssb[0];
        for (int i = 1; i < 4; ++i) {
            float nm = fmaxf(M, sm[i]);
            SS = SS * __expf(M - nm) + ssb[i] * __expf(sm[i] - nm);
            M = nm;
        }
        lse[row] = M + logf(SS);
    }
}

// ------------------------------------------------------- subtract lse -------
__global__ __launch_bounds__(256) void k_sub(float* __restrict__ y,
                                             const float* __restrict__ lse) {
    int i4 = blockIdx.x * 256 + threadIdx.x;   // float4 index, NLOC/4=12500 per row
    int row = i4 / 12500;
    float l = lse[row];
    float4* p = (float4*)y + i4;
    float4 v = *p;
    v.x -= l; v.y -= l; v.z -= l; v.w -= l;
    *p = v;
}

// ---------------------------------------------------------------------------
extern "C" void kernel_launch(void* const* d_in, const int* in_sizes, int n_in,
                              void* d_out, int out_size, void* d_ws, size_t ws_size,
                              hipStream_t stream) {
    const int* loc  = (const int*)d_in[0];
    const int* tim  = (const int*)d_in[1];
    const int* clu  = (const int*)d_in[2];
    const int* hloc = (const int*)d_in[3];
    const int* hclu = (const int*)d_in[4];
    const int* htim = (const int*)d_in[5];
    const int* hcnt = (const int*)d_in[6];
    const int* uid  = (const int*)d_in[7];
    const float* emb_loc    = (const float*)d_in[9];
    const float* emb_tim    = (const float*)d_in[10];
    const float* emb_clu    = (const float*)d_in[11];
    const float* emb_uid    = (const float*)d_in[12];
    const float* fc_attn_w  = (const float*)d_in[13];
    const float* fc_attn_b  = (const float*)d_in[14];
    const float* w_ih       = (const float*)d_in[15];
    const float* w_hh       = (const float*)d_in[16];
    const float* b_ih       = (const float*)d_in[17];
    const float* b_hh       = (const float*)d_in[18];
    const float* fc_final_w = (const float*)d_in[19];
    const float* fc_final_b = (const float*)d_in[20];
    float* y = (float*)d_out;

    float* feats  = (float*)d_ws;                 // G_NUM * INP
    float* xf     = feats + G_NUM * INP;          // S_LEN * INP
    float* hist   = xf + S_LEN * INP;             // G_NUM * HID
    float* gx     = hist + G_NUM * HID;           // S_LEN * 1536
    float* hbuf   = gx + S_LEN * 1536;            // 2 * HID
    float* outmat = hbuf + 2 * HID;               // T_LEN * OUTD
    float* lse    = outmat + T_LEN * OUTD;        // T_LEN
    __hip_bfloat16* outbf = (__hip_bfloat16*)(lse + T_LEN);          // T_LEN*OUTD bf16
    int* cnt  = (int*)((char*)outbf + (size_t)T_LEN * OUTD * 2);     // S_LEN ints
    int* offs = cnt + S_LEN;                                         // G_NUM ints

    k_init<<<1, 1024, 0, stream>>>(cnt, hbuf, hcnt, offs);
    k_feats<<<G_NUM, 256, 0, stream>>>(hloc, hclu, htim, hcnt, offs,
                                       emb_loc, emb_clu, emb_tim, feats);
    k_xfeat<<<S_LEN, 256, 0, stream>>>(loc, clu, tim, emb_loc, emb_clu, emb_tim, xf);
    k_gemm8<<<dim3(G_NUM / 8, 1), 256, 0, stream>>>(feats, fc_attn_w, fc_attn_b,
                                                    hist, HID, 1);
    k_gemm8<<<dim3(S_LEN / 8, 3), 256, 0, stream>>>(xf, w_ih, b_ih, gx, 1536, 0);
    k_gru<<<GRU_WGS, 256, 0, stream>>>(w_hh, b_hh, gx, hbuf, outmat, cnt);
    k_attn<<<T_LEN / 8, 256, 0, stream>>>(hist, emb_uid, uid, outmat);
    k_cvt<<<(T_LEN * OUTD + 255) / 256, 256, 0, stream>>>(outmat, outbf, T_LEN * OUTD);
    k_final<<<(NLOC + 63) / 64, 256, 0, stream>>>(outbf, fc_final_w, fc_final_b, y);
    k_lse<<<T_LEN, 256, 0, stream>>>(y, lse);
    k_sub<<<(T_LEN * (NLOC / 4)) / 256, 256, 0, stream>>>(y, lse);
}

// Round 2
// 3474.843 us; speedup vs baseline: 1.8402x; 1.8402x over previous
//
#include <hip/hip_runtime.h>
#include <hip/hip_bf16.h>
#include <math.h>

#define S_LEN 1024
#define T_LEN 512
#define G_NUM 1024
#define NLOC  50000
#define HID   512
#define INP   608     // 512 + 64 + 32
#define OUTD  1088    // 2*HID + 64
#define GRU_WGS 32

typedef float f32x4 __attribute__((ext_vector_type(4)));
typedef short bf16x8 __attribute__((ext_vector_type(8)));

// ---------------------------------------------------------------- init ------
__global__ __launch_bounds__(1024) void k_init(const int* counts, int* offs) {
    __shared__ int sh[1024];
    int tid = threadIdx.x;
    sh[tid] = counts[tid];
    __syncthreads();
    for (int st = 1; st < 1024; st <<= 1) {
        int v = (tid >= st) ? sh[tid - st] : 0;
        __syncthreads();
        sh[tid] += v;
        __syncthreads();
    }
    offs[tid] = sh[tid] - counts[tid];   // exclusive prefix
}

// ------------------------------------------------------- history features ---
__global__ __launch_bounds__(256) void k_feats(
    const int* __restrict__ hloc, const int* __restrict__ hclu,
    const int* __restrict__ htim, const int* __restrict__ counts,
    const int* __restrict__ offs,
    const float* __restrict__ emb_loc, const float* __restrict__ emb_clu,
    const float* __restrict__ emb_tim, float* __restrict__ feats) {
    int g = blockIdx.x, tid = threadIdx.x;
    __shared__ int iloc[64], iclu[64];
    __shared__ int itim0;
    int off = offs[g], cn = counts[g];
    if (tid < cn) { iloc[tid] = hloc[off + tid]; iclu[tid] = hclu[off + tid]; }
    if (tid == 0) itim0 = htim[off];
    __syncthreads();
    float inv = 1.0f / (float)cn;
    for (int d = tid; d < 512; d += 256) {
        float s = 0.f;
        for (int i = 0; i < cn; ++i) s += emb_loc[iloc[i] * 512 + d];
        feats[g * INP + d] = s * inv;
    }
    for (int d = tid; d < 64; d += 256) {
        float s = 0.f;
        for (int i = 0; i < cn; ++i) s += emb_clu[iclu[i] * 64 + d];
        feats[g * INP + 512 + d] = s * inv;
    }
    for (int d = tid; d < 32; d += 256)
        feats[g * INP + 576 + d] = emb_tim[itim0 * 32 + d];
}

// ------------------------------------------------------------ x features ----
__global__ __launch_bounds__(256) void k_xfeat(
    const int* __restrict__ loc, const int* __restrict__ clu,
    const int* __restrict__ tim,
    const float* __restrict__ emb_loc, const float* __restrict__ emb_clu,
    const float* __restrict__ emb_tim, float* __restrict__ x) {
    int s = blockIdx.x, tid = threadIdx.x;
    int il = loc[s], ic = clu[s], it = tim[s];
    for (int d = tid; d < 512; d += 256) x[s * INP + d] = emb_loc[il * 512 + d];
    for (int d = tid; d < 64; d += 256) x[s * INP + 512 + d] = emb_clu[ic * 64 + d];
    for (int d = tid; d < 32; d += 256) x[s * INP + 576 + d] = emb_tim[it * 32 + d];
}

// ---------------------------------------------- generic 8-row fp32 GEMM -----
__global__ __launch_bounds__(256) void k_gemm8(
    const float* __restrict__ A, const float* __restrict__ W,
    const float* __restrict__ bias, float* __restrict__ out,
    int ldout, int act) {
    __shared__ float ash[8][INP];
    int r0 = blockIdx.x * 8, c0 = blockIdx.y * 512;
    int tid = threadIdx.x;
    for (int i = tid; i < 8 * INP; i += 256)
        ash[i / INP][i % INP] = A[(r0 + i / INP) * INP + (i % INP)];
    __syncthreads();
    for (int cc = 0; cc < 2; ++cc) {
        int c = c0 + cc * 256 + tid;
        float acc[8];
#pragma unroll
        for (int r = 0; r < 8; ++r) acc[r] = 0.f;
        const float* wr = &W[(long)c * INP];
        for (int k = 0; k < INP; k += 4) {
            float4 wv = *(const float4*)&wr[k];
#pragma unroll
            for (int r = 0; r < 8; ++r) {
                float4 av = *(const float4*)&ash[r][k];
                acc[r] += av.x * wv.x + av.y * wv.y + av.z * wv.z + av.w * wv.w;
            }
        }
#pragma unroll
        for (int r = 0; r < 8; ++r) {
            float v = acc[r] + bias[c];
            if (act) v = tanhf(v);
            out[(long)(r0 + r) * ldout + c] = v;
        }
    }
}

// ------------------------------------------------------------- GRU ----------
// 32 WGs x 256 thr. Output j = wg*16 + grp (grp = tid>>4). Weights in VGPRs:
// thread (grp,lane) holds w[gate][j][k] for k = m*64 + lane*4 + i (m<8, i<4).
// h exchange: packed (tag<<32 | float bits) 8B words, double-buffered; relaxed
// agent atomics only — data and flag arrive together, no fences, no fetch_add.
__global__ __launch_bounds__(256, 1) void k_gru(
    const float* __restrict__ w_hh, const float* __restrict__ b_hh,
    const float* __restrict__ gx, unsigned long long* __restrict__ tb,
    float* __restrict__ outmat) {
    __shared__ float hsh[512];
    const int wg = blockIdx.x, tid = threadIdx.x;
    const int grp = tid >> 4, lane = tid & 15;
    const int j = wg * 16 + grp;

    float4 wr[8], wz[8], wn[8];
#pragma unroll
    for (int m = 0; m < 8; ++m) {
        wr[m] = *(const float4*)&w_hh[(long)(0 * 512 + j) * 512 + m * 64 + lane * 4];
        wz[m] = *(const float4*)&w_hh[(long)(1 * 512 + j) * 512 + m * 64 + lane * 4];
        wn[m] = *(const float4*)&w_hh[(long)(2 * 512 + j) * 512 + m * 64 + lane * 4];
    }
    const float bhr = b_hh[j], bhz = b_hh[512 + j], bhn = b_hh[1024 + j];
    hsh[tid] = 0.f; hsh[tid + 256] = 0.f;
    __syncthreads();

    for (int t = 0; t < S_LEN; ++t) {
        // gx loads issued early; resolve during poll wait
        float xr = gx[t * 1536 + j];
        float xz = gx[t * 1536 + 512 + j];
        float xn = gx[t * 1536 + 1024 + j];
        if (t > 0) {
            const unsigned int want = (unsigned int)(t - 1);
            const unsigned long long* b = tb + (((t - 1) & 1) << 9);
            unsigned long long v0 = __hip_atomic_load(b + tid, __ATOMIC_RELAXED,
                                                      __HIP_MEMORY_SCOPE_AGENT);
            while ((unsigned int)(v0 >> 32) != want)
                v0 = __hip_atomic_load(b + tid, __ATOMIC_RELAXED,
                                       __HIP_MEMORY_SCOPE_AGENT);
            unsigned long long v1 = __hip_atomic_load(b + tid + 256, __ATOMIC_RELAXED,
                                                      __HIP_MEMORY_SCOPE_AGENT);
            while ((unsigned int)(v1 >> 32) != want)
                v1 = __hip_atomic_load(b + tid + 256, __ATOMIC_RELAXED,
                                       __HIP_MEMORY_SCOPE_AGENT);
            hsh[tid] = __uint_as_float((unsigned int)v0);
            hsh[tid + 256] = __uint_as_float((unsigned int)v1);
        }
        __syncthreads();
        float sr = 0.f, sz = 0.f, sn = 0.f;
#pragma unroll
        for (int m = 0; m < 8; ++m) {
            float4 hv = *(const float4*)&hsh[m * 64 + lane * 4];
            sr += wr[m].x * hv.x + wr[m].y * hv.y + wr[m].z * hv.z + wr[m].w * hv.w;
            sz += wz[m].x * hv.x + wz[m].y * hv.y + wz[m].z * hv.z + wz[m].w * hv.w;
            sn += wn[m].x * hv.x + wn[m].y * hv.y + wn[m].z * hv.z + wn[m].w * hv.w;
        }
#pragma unroll
        for (int off = 8; off; off >>= 1) {
            sr += __shfl_xor(sr, off);
            sz += __shfl_xor(sz, off);
            sn += __shfl_xor(sn, off);
        }
        if (lane == 0) {
            float r = 1.f / (1.f + __expf(-(xr + sr + bhr)));
            float z = 1.f / (1.f + __expf(-(xz + sz + bhz)));
            float n = tanhf(xn + r * (sn + bhn));
            float hold = hsh[j];
            float hnew = (1.f - z) * n + z * hold;
            unsigned long long pk =
                ((unsigned long long)(unsigned int)t << 32) | __float_as_uint(hnew);
            __hip_atomic_store(tb + ((t & 1) << 9) + j, pk, __ATOMIC_RELAXED,
                               __HIP_MEMORY_SCOPE_AGENT);
            if (t >= S_LEN - T_LEN) outmat[(t - (S_LEN - T_LEN)) * OUTD + j] = hnew;
        }
        __syncthreads();   // protect hsh reads from next step's poll writes
    }
}

// ------------------------------------------------------- attention ----------
__global__ __launch_bounds__(256) void k_attn(
    const float* __restrict__ history, const float* __restrict__ emb_uid,
    const int* __restrict__ uid, float* __restrict__ outmat) {
    __shared__ float qsh[8][512];
    __shared__ float psh[8][1024];
    __shared__ float sc[4];
    int r0 = blockIdx.x * 8, tid = threadIdx.x;
    for (int i = tid; i < 8 * 512; i += 256)
        qsh[i >> 9][i & 511] = outmat[(r0 + (i >> 9)) * OUTD + (i & 511)];
    __syncthreads();
    for (int cc = 0; cc < 4; ++cc) {
        int g = cc * 256 + tid;
        float acc[8];
#pragma unroll
        for (int r = 0; r < 8; ++r) acc[r] = 0.f;
        const float* hrow = &history[g * 512];
        for (int k = 0; k < 512; k += 4) {
            float4 hv = *(const float4*)&hrow[k];
#pragma unroll
            for (int r = 0; r < 8; ++r) {
                float4 qv = *(const float4*)&qsh[r][k];
                acc[r] += qv.x * hv.x + qv.y * hv.y + qv.z * hv.z + qv.w * hv.w;
            }
        }
#pragma unroll
        for (int r = 0; r < 8; ++r) psh[r][g] = acc[r];
    }
    __syncthreads();
    for (int r = 0; r < 8; ++r) {
        float m = -1e30f;
        for (int cc = 0; cc < 4; ++cc) m = fmaxf(m, psh[r][cc * 256 + tid]);
#pragma unroll
        for (int off = 32; off; off >>= 1) m = fmaxf(m, __shfl_xor(m, off));
        if ((tid & 63) == 0) sc[tid >> 6] = m;
        __syncthreads();
        m = fmaxf(fmaxf(sc[0], sc[1]), fmaxf(sc[2], sc[3]));
        __syncthreads();
        float ss = 0.f;
        for (int cc = 0; cc < 4; ++cc) {
            int g = cc * 256 + tid;
            float e = __expf(psh[r][g] - m);
            psh[r][g] = e;
            ss += e;
        }
#pragma unroll
        for (int off = 32; off; off >>= 1) ss += __shfl_xor(ss, off);
        if ((tid & 63) == 0) sc[tid >> 6] = ss;
        __syncthreads();
        ss = sc[0] + sc[1] + sc[2] + sc[3];
        float inv = 1.f / ss;
        for (int cc = 0; cc < 4; ++cc) psh[r][cc * 256 + tid] *= inv;
        __syncthreads();
    }
    for (int dd = 0; dd < 2; ++dd) {
        int d = dd * 256 + tid;
        float acc[8];
#pragma unroll
        for (int r = 0; r < 8; ++r) acc[r] = 0.f;
        for (int g = 0; g < 1024; ++g) {
            float hv = history[g * 512 + d];
#pragma unroll
            for (int r = 0; r < 8; ++r) acc[r] += psh[r][g] * hv;
        }
#pragma unroll
        for (int r = 0; r < 8; ++r) outmat[(r0 + r) * OUTD + 512 + d] = acc[r];
    }
    int u = uid[0];
    for (int i = tid; i < 8 * 64; i += 256)
        outmat[(r0 + (i >> 6)) * OUTD + 1024 + (i & 63)] = emb_uid[u * 64 + (i & 63)];
}

// ----------------------------------------------------------- f32 -> bf16 ----
__global__ __launch_bounds__(256) void k_cvt(const float* __restrict__ in,
                                             __hip_bfloat16* __restrict__ out, int n) {
    int i = blockIdx.x * 256 + threadIdx.x;
    if (i < n) out[i] = __float2bfloat16(in[i]);
}

// -------------------------------------------- final GEMM (bf16 MFMA) --------
__global__ __launch_bounds__(256, 2) void k_final(
    const __hip_bfloat16* __restrict__ Abf, const float* __restrict__ Wf,
    const float* __restrict__ bias, float* __restrict__ y) {
    __shared__ __hip_bfloat16 ash[512 * 40];
    __shared__ __hip_bfloat16 bsh[64 * 40];
    const int n0 = blockIdx.x * 64;
    const int tid = threadIdx.x;
    const int wave = tid >> 6, lane = tid & 63;
    f32x4 acc[32];
#pragma unroll
    for (int i = 0; i < 32; ++i) acc[i] = (f32x4){0.f, 0.f, 0.f, 0.f};

    for (int kc = 0; kc < 34; ++kc) {
        const int k0 = kc * 32;
        __syncthreads();
#pragma unroll
        for (int rr = 0; rr < 2; ++rr) {
            int r = tid + rr * 256;
            const uint4* src = (const uint4*)(Abf + r * OUTD + k0);
            uint4 v0 = src[0], v1 = src[1], v2 = src[2], v3 = src[3];
            uint4* dst = (uint4*)(ash + r * 40);
            dst[0] = v0; dst[1] = v1; dst[2] = v2; dst[3] = v3;
        }
        {
            int rb = tid >> 2, q = tid & 3;
            int n = n0 + rb;
            float4 w0 = {0.f, 0.f, 0.f, 0.f}, w1 = {0.f, 0.f, 0.f, 0.f};
            if (n < NLOC) {
                const float4* wsrc = (const float4*)(Wf + (long)n * OUTD + k0 + q * 8);
                w0 = wsrc[0]; w1 = wsrc[1];
            }
            __hip_bfloat16* bd = bsh + rb * 40 + q * 8;
            bd[0] = __float2bfloat16(w0.x); bd[1] = __float2bfloat16(w0.y);
            bd[2] = __float2bfloat16(w0.z); bd[3] = __float2bfloat16(w0.w);
            bd[4] = __float2bfloat16(w1.x); bd[5] = __float2bfloat16(w1.y);
            bd[6] = __float2bfloat16(w1.z); bd[7] = __float2bfloat16(w1.w);
        }
        __syncthreads();
        const int nlane = lane & 15, quad = lane >> 4;
        bf16x8 bfrag = *(const bf16x8*)(bsh + (wave * 16 + nlane) * 40 + quad * 8);
#pragma unroll
        for (int mt = 0; mt < 32; ++mt) {
            bf16x8 afrag = *(const bf16x8*)(ash + (mt * 16 + nlane) * 40 + quad * 8);
            acc[mt] = __builtin_amdgcn_mfma_f32_16x16x32_bf16(afrag, bfrag, acc[mt], 0, 0, 0);
        }
    }
    const int nlane = lane & 15, quad = lane >> 4;
    const int col = n0 + wave * 16 + nlane;
    if (col < NLOC) {
        float bv = bias[col];
#pragma unroll
        for (int mt = 0; mt < 32; ++mt) {
            int rbase = mt * 16 + quad * 4;
#pragma unroll
            for (int i = 0; i < 4; ++i)
                y[(rbase + i) * NLOC + col] = acc[mt][i] + bv;
        }
    }
}

// ----------------------------------------------------------- row LSE --------
__global__ __launch_bounds__(256) void k_lse(const float* __restrict__ y,
                                             float* __restrict__ lse) {
    __shared__ float sm[4], ssb[4];
    int row = blockIdx.x, tid = threadIdx.x;
    const float* rp = y + (long)row * NLOC;
    float m = -1e30f, s = 0.f;
    for (int i = tid * 4; i < NLOC; i += 1024) {
        float4 v = *(const float4*)&rp[i];
        float mv = fmaxf(fmaxf(v.x, v.y), fmaxf(v.z, v.w));
        if (mv > m) { s *= __expf(m - mv); m = mv; }
        s += __expf(v.x - m) + __expf(v.y - m) + __expf(v.z - m) + __expf(v.w - m);
    }
#pragma unroll
    for (int off = 32; off; off >>= 1) {
        float om = __shfl_xor(m, off), os = __shfl_xor(s, off);
        float nm = fmaxf(m, om);
        s = s * __expf(m - nm) + os * __expf(om - nm);
        m = nm;
    }
    if ((tid & 63) == 0) { sm[tid >> 6] = m; ssb[tid >> 6] = s; }
    __syncthreads();
    if (tid == 0) {
        float M = sm[0], SS = ssb[0];
        for (int i = 1; i < 4; ++i) {
            float nm = fmaxf(M, sm[i]);
            SS = SS * __expf(M - nm) + ssb[i] * __expf(sm[i] - nm);
            M = nm;
        }
        lse[row] = M + logf(SS);
    }
}

// ------------------------------------------------------- subtract lse -------
__global__ __launch_bounds__(256) void k_sub(float* __restrict__ y,
                                             const float* __restrict__ lse) {
    int i4 = blockIdx.x * 256 + threadIdx.x;
    int row = i4 / 12500;
    float l = lse[row];
    float4* p = (float4*)y + i4;
    float4 v = *p;
    v.x -= l; v.y -= l; v.z -= l; v.w -= l;
    *p = v;
}

// ---------------------------------------------------------------------------
extern "C" void kernel_launch(void* const* d_in, const int* in_sizes, int n_in,
                              void* d_out, int out_size, void* d_ws, size_t ws_size,
                              hipStream_t stream) {
    const int* loc  = (const int*)d_in[0];
    const int* tim  = (const int*)d_in[1];
    const int* clu  = (const int*)d_in[2];
    const int* hloc = (const int*)d_in[3];
    const int* hclu = (const int*)d_in[4];
    const int* htim = (const int*)d_in[5];
    const int* hcnt = (const int*)d_in[6];
    const int* uid  = (const int*)d_in[7];
    const float* emb_loc    = (const float*)d_in[9];
    const float* emb_tim    = (const float*)d_in[10];
    const float* emb_clu    = (const float*)d_in[11];
    const float* emb_uid    = (const float*)d_in[12];
    const float* fc_attn_w  = (const float*)d_in[13];
    const float* fc_attn_b  = (const float*)d_in[14];
    const float* w_ih       = (const float*)d_in[15];
    const float* w_hh       = (const float*)d_in[16];
    const float* b_ih       = (const float*)d_in[17];
    const float* b_hh       = (const float*)d_in[18];
    const float* fc_final_w = (const float*)d_in[19];
    const float* fc_final_b = (const float*)d_in[20];
    float* y = (float*)d_out;

    float* feats  = (float*)d_ws;                 // 1024*608
    float* xf     = feats + G_NUM * INP;          // 1024*608
    float* hist   = xf + S_LEN * INP;             // 1024*512
    float* gx     = hist + G_NUM * HID;           // 1024*1536
    float* outmat = gx + S_LEN * 1536;            // 512*1088
    float* lse    = outmat + T_LEN * OUTD;        // 512
    unsigned long long* tb = (unsigned long long*)(lse + T_LEN);     // 2*512 u64 (8B-aligned)
    __hip_bfloat16* outbf = (__hip_bfloat16*)(tb + 2 * 512);         // 512*1088 bf16
    int* offs = (int*)((char*)outbf + (size_t)T_LEN * OUTD * 2);     // 1024 ints

    k_init<<<1, 1024, 0, stream>>>(hcnt, offs);
    k_feats<<<G_NUM, 256, 0, stream>>>(hloc, hclu, htim, hcnt, offs,
                                       emb_loc, emb_clu, emb_tim, feats);
    k_xfeat<<<S_LEN, 256, 0, stream>>>(loc, clu, tim, emb_loc, emb_clu, emb_tim, xf);
    k_gemm8<<<dim3(G_NUM / 8, 1), 256, 0, stream>>>(feats, fc_attn_w, fc_attn_b,
                                                    hist, HID, 1);
    k_gemm8<<<dim3(S_LEN / 8, 3), 256, 0, stream>>>(xf, w_ih, b_ih, gx, 1536, 0);
    k_gru<<<GRU_WGS, 256, 0, stream>>>(w_hh, b_hh, gx, tb, outmat);
    k_attn<<<T_LEN / 8, 256, 0, stream>>>(hist, emb_uid, uid, outmat);
    k_cvt<<<(T_LEN * OUTD + 255) / 256, 256, 0, stream>>>(outmat, outbf, T_LEN * OUTD);
    k_final<<<(NLOC + 63) / 64, 256, 0, stream>>>(outbf, fc_final_w, fc_final_b, y);
    k_lse<<<T_LEN, 256, 0, stream>>>(y, lse);
    k_sub<<<(T_LEN * (NLOC / 4)) / 256, 256, 0, stream>>>(y, lse);
}